// Round 1
// baseline (573.026 us; speedup 1.0000x reference)
//
#include <hip/hip_runtime.h>
#include <stdint.h>

#define BB 64
#define VV 50257
#define DD 1024
#define OUTOFF 128               // token_ids[64] + token_logprobs[64]
#define MASKW ((VV + 31) / 32)   // 1571
#define CAP 3072
#define NSORT 4096
#define TINYF 1.17549435e-38f

// ---------------- JAX threefry2x32 (key(42) = {0,42}) ----------------
__device__ __forceinline__ uint32_t rotl32(uint32_t x, int d) {
  return (x << d) | (x >> (32 - d));
}

__device__ __forceinline__ void threefry2x32(uint32_t k0, uint32_t k1,
                                             uint32_t x0, uint32_t x1,
                                             uint32_t& o0, uint32_t& o1) {
  uint32_t ks2 = k0 ^ k1 ^ 0x1BD11BDAu;
#define TFR(r) { x0 += x1; x1 = rotl32(x1, (r)); x1 ^= x0; }
  x0 += k0; x1 += k1;
  TFR(13) TFR(15) TFR(26) TFR(6)
  x0 += k1; x1 += ks2 + 1u;
  TFR(17) TFR(29) TFR(16) TFR(24)
  x0 += ks2; x1 += k0 + 2u;
  TFR(13) TFR(15) TFR(26) TFR(6)
  x0 += k0; x1 += k1 + 3u;
  TFR(17) TFR(29) TFR(16) TFR(24)
  x0 += k1; x1 += ks2 + 4u;
  TFR(13) TFR(15) TFR(26) TFR(6)
  x0 += ks2; x1 += k0 + 5u;
#undef TFR
  o0 = x0; o1 = x1;
}

// Gumbel noise for flat element index i of a (64,50257) f32 draw under
// jax_threefry_partitionable=True (default since JAX 0.4.36):
//   (o0,o1) = threefry(key, (hi64(i)=0, lo64(i)=i)); bits = o0 ^ o1
// FALLBACK (classic, pre-0.4.36): half = N/2;
//   i<half:  bits = o0 of threefry(key,(i, i+half))
//   i>=half: bits = o1 of threefry(key,(i-half, i))
__device__ __forceinline__ float jax_gumbel(uint32_t flat_idx) {
  uint32_t o0, o1;
  threefry2x32(0u, 42u, 0u, flat_idx, o0, o1);
  uint32_t bits = o0 ^ o1;
  // uniform(minval=tiny, maxval=1): u in [0, 1-2^-23], then u*1.0f + tiny, max(tiny, .)
  float u = __uint_as_float((bits >> 9) | 0x3F800000u) - 1.0f;
  float u2 = fmaxf(TINYF, u + TINYF);
  return -logf(-logf(u2));
}

// order-preserving uint encoding of float (for atomicMax row-max)
__device__ __forceinline__ uint32_t ordEnc(float f) {
  uint32_t u = __float_as_uint(f);
  return (u & 0x80000000u) ? ~u : (u | 0x80000000u);
}
__device__ __forceinline__ float ordDec(uint32_t u) {
  uint32_t fb = (u & 0x80000000u) ? (u & 0x7FFFFFFFu) : ~u;
  return __uint_as_float(fb);
}

// ---------------- K0: init ws row-max accumulators ----------------
__global__ void k_init(uint32_t* __restrict__ wsMax) {
  wsMax[threadIdx.x] = 0u;  // ordEnc lower bound
}

// ---------------- K1: logits = (hid . emb^T) / temp, fused row-max ----------------
// grid: ceil(V/64) blocks x 256 threads. C tile: 64 rows(b) x 64 cols(v).
__global__ __launch_bounds__(256) void k_gemm(
    const float* __restrict__ hid, const float* __restrict__ emb,
    const float* __restrict__ temps, float* __restrict__ outF,
    uint32_t* __restrict__ wsMax) {
  __shared__ float As[64][36];  // +4 pad: conflict-free b128 reads (144B rows)
  __shared__ float Es[64][36];
  __shared__ uint32_t bmax[64];
  const int tid = threadIdx.x;
  const int v0 = blockIdx.x * 64;
  if (tid < 64) bmax[tid] = 0u;
  const int lane = tid & 63, w = tid >> 6;
  const int bbase = (lane >> 4) + (w << 2);  // 0..15
  const int vbase = lane & 15;               // 0..15
  float acc[4][4] = {};
  for (int k0 = 0; k0 < DD; k0 += 32) {
    __syncthreads();
    for (int q = tid; q < 512; q += 256) {  // 64 rows x 8 float4
      int r = q >> 3, c4 = (q & 7) << 2;
      *(float4*)(&As[r][c4]) = *(const float4*)(hid + r * DD + k0 + c4);
    }
    for (int q = tid; q < 512; q += 256) {
      int r = q >> 3, c4 = (q & 7) << 2;
      int vv = v0 + r;
      float4 val = make_float4(0.f, 0.f, 0.f, 0.f);
      if (vv < VV) val = *(const float4*)(emb + (size_t)vv * DD + k0 + c4);
      *(float4*)(&Es[r][c4]) = val;
    }
    __syncthreads();
#pragma unroll
    for (int kk = 0; kk < 32; kk += 4) {
      float4 a[4], e[4];
#pragma unroll
      for (int i = 0; i < 4; i++) a[i] = *(float4*)(&As[bbase + 16 * i][kk]);
#pragma unroll
      for (int j = 0; j < 4; j++) e[j] = *(float4*)(&Es[vbase + 16 * j][kk]);
#pragma unroll
      for (int i = 0; i < 4; i++)
#pragma unroll
        for (int j = 0; j < 4; j++)
          acc[i][j] += a[i].x * e[j].x + a[i].y * e[j].y +
                       a[i].z * e[j].z + a[i].w * e[j].w;
    }
  }
  float tb[4];
#pragma unroll
  for (int i = 0; i < 4; i++) tb[i] = temps[bbase + 16 * i];
  uint32_t lm[4] = {0u, 0u, 0u, 0u};
#pragma unroll
  for (int i = 0; i < 4; i++) {
    int b = bbase + 16 * i;
#pragma unroll
    for (int j = 0; j < 4; j++) {
      int vv = v0 + vbase + 16 * j;
      if (vv < VV) {
        float c = acc[i][j] / tb[i];  // IEEE divide, matches ref logits/temp
        outF[OUTOFF + (size_t)b * VV + vv] = c;
        uint32_t e = ordEnc(c);
        if (e > lm[i]) lm[i] = e;
      }
    }
  }
  __syncthreads();
#pragma unroll
  for (int i = 0; i < 4; i++) atomicMax(&bmax[bbase + 16 * i], lm[i]);
  __syncthreads();
  if (tid < 64) atomicMax(&wsMax[tid], bmax[tid]);
}

// ---------------- K2: per-row Z = sum(exp(l - M)) ----------------
__global__ __launch_bounds__(1024) void k_sumexp(
    const float* __restrict__ outF, const uint32_t* __restrict__ wsMax,
    float* __restrict__ wsM, float* __restrict__ wsZ) {
  const int b = blockIdx.x, tid = threadIdx.x;
  float M = ordDec(wsMax[b]);
  const float* row = outF + OUTOFF + (size_t)b * VV;
  float s = 0.f;
  for (int v = tid; v < VV; v += 1024) s += expf(row[v] - M);
  __shared__ float red[1024];
  red[tid] = s;
  __syncthreads();
  for (int off = 512; off > 0; off >>= 1) {
    if (tid < off) red[tid] += red[tid + off];
    __syncthreads();
  }
  if (tid == 0) { wsM[b] = M; wsZ[b] = red[0]; }
}

// ---------------- K3: top-k select, top-p check, gumbel sample, fprobs write ----------------
// one block (1024 thr) per row b
__global__ __launch_bounds__(1024) void k_select(
    float* __restrict__ outF, const float* __restrict__ wsM,
    const float* __restrict__ wsZ, const float* __restrict__ top_ps,
    const int* __restrict__ top_ks) {
  const int b = blockIdx.x, tid = threadIdx.x;
  const float M = wsM[b], Z = wsZ[b];
  float* row = outF + OUTOFF + (size_t)b * VV;  // holds logits, becomes fprobs
  const int k_need = min(top_ks[b], 1023);
  const float top_p = top_ps[b];

  __shared__ uint32_t hist[2048];   // bins = pbits>>19 (p<1 => bin<2048)
  __shared__ uint64_t cand[NSORT];  // (pbits<<32)|~v : desc value, asc index
  __shared__ float pf[1024];
  __shared__ int redi[1024];
  __shared__ float redf[1024];
  __shared__ uint32_t kmask[MASKW];
  __shared__ int s_b1, s_count;

  // Phase A: histogram of prob bit-bins
  for (int i = tid; i < 2048; i += 1024) hist[i] = 0u;
  __syncthreads();
  for (int v = tid; v < VV; v += 1024) {
    float p = expf(row[v] - M) / Z;
    atomicAdd(&hist[__float_as_uint(p) >> 19], 1u);
  }
  __syncthreads();
  // Phase B: boundary bin b1: above(b1) < k <= above(b1)+cnt(b1)
  uint32_t c0 = hist[tid * 2], c1 = hist[tid * 2 + 1];
  redi[tid] = (int)(c0 + c1);
  __syncthreads();
  for (int off = 1; off < 1024; off <<= 1) {  // inclusive suffix scan
    int y = (tid + off < 1024) ? redi[tid + off] : 0;
    __syncthreads();
    redi[tid] += y;
    __syncthreads();
  }
  {
    int aboveHi = (tid + 1 < 1024) ? redi[tid + 1] : 0;
    int a1 = aboveHi, a0 = aboveHi + (int)c1;
    if (a1 < k_need && a1 + (int)c1 >= k_need) s_b1 = tid * 2 + 1;
    if (a0 < k_need && a0 + (int)c0 >= k_need) s_b1 = tid * 2;
  }
  if (tid == 0) s_count = 0;
  __syncthreads();
  const int b1 = s_b1;
  // Phase C: collect candidates (bin >= b1)
  for (int v = tid; v < VV; v += 1024) {
    float p = expf(row[v] - M) / Z;
    uint32_t pb = __float_as_uint(p);
    if ((int)(pb >> 19) >= b1) {
      int pos = atomicAdd(&s_count, 1);
      if (pos < CAP)
        cand[pos] = ((uint64_t)pb << 32) | (uint64_t)(~(uint32_t)v);
    }
  }
  __syncthreads();
  const int ncand = min(s_count, CAP);
  for (int i = tid; i < NSORT; i += 1024)
    if (i >= ncand) cand[i] = 0ull;
  __syncthreads();
  // Phase D: bitonic sort descending (64-bit keys)
  for (int k = 2; k <= NSORT; k <<= 1) {
    for (int j = k >> 1; j > 0; j >>= 1) {
      for (int i = tid; i < NSORT; i += 1024) {
        int ixj = i ^ j;
        if (ixj > i) {
          uint64_t x = cand[i], y = cand[ixj];
          bool up = ((i & k) == 0);
          if (up ? (x < y) : (x > y)) { cand[i] = y; cand[ixj] = x; }
        }
      }
      __syncthreads();
    }
  }
  // Phase E: prefix over sorted top-k_eff, find first rank with excl>top_p
  const int k_eff = min(k_need, ncand);
  uint64_t mykey = cand[tid];
  float pr = (tid < k_eff) ? __uint_as_float((uint32_t)(mykey >> 32)) : 0.f;
  pf[tid] = pr;
  __syncthreads();
  float incl = pr;
  for (int off = 1; off < 1024; off <<= 1) {
    float y = (tid >= off) ? pf[tid - off] : 0.f;
    __syncthreads();
    incl += y;
    pf[tid] = incl;
    __syncthreads();
  }
  redi[tid] = (tid < k_eff && (incl - pr) > top_p) ? tid : 0x7FFFFFFF;
  __syncthreads();
  for (int s = 512; s > 0; s >>= 1) {
    if (tid < s) redi[tid] = min(redi[tid], redi[tid + s]);
    __syncthreads();
  }
  const int nstar = min(redi[0], k_eff);  // kept ranks [0, nstar)
  __syncthreads();
  // Phase F: gumbel-argmax over kept ranks (ties -> smallest token index)
  float score = -INFINITY;
  int svtok = 0x7FFFFFFF;
  if (tid < nstar) {
    float p = __uint_as_float((uint32_t)(mykey >> 32));
    uint32_t v = ~(uint32_t)(mykey & 0xFFFFFFFFull);
    float fl = logf(fmaxf(p, 1e-38f));
    score = fl + jax_gumbel((uint32_t)b * (uint32_t)VV + v);
    svtok = (int)v;
  }
  redf[tid] = score;
  redi[tid] = svtok;
  __syncthreads();
  for (int s = 512; s > 0; s >>= 1) {
    if (tid < s) {
      float s2 = redf[tid + s];
      int v2 = redi[tid + s];
      if (s2 > redf[tid] || (s2 == redf[tid] && v2 < redi[tid])) {
        redf[tid] = s2;
        redi[tid] = v2;
      }
    }
    __syncthreads();
  }
  if (tid == 0) {
    int t = redi[0];
    float lt = row[t];  // still logits here
    outF[b] = (float)t; // token_ids as f32 (exact, V < 2^24)
    outF[64 + b] = lt - M - logf(Z);
  }
  // Phase G: membership bitmask, then rewrite row as fprobs
  for (int i = tid; i < MASKW; i += 1024) kmask[i] = 0u;
  __syncthreads();
  if (tid < nstar) {
    uint32_t v = ~(uint32_t)(mykey & 0xFFFFFFFFull);
    atomicOr(&kmask[v >> 5], 1u << (v & 31));
  }
  __syncthreads();
  for (int v = tid; v < VV; v += 1024) {
    float p = expf(row[v] - M) / Z;
    bool keep = (kmask[v >> 5] >> (v & 31)) & 1u;
    row[v] = keep ? p : 0.0f;
  }
}

extern "C" void kernel_launch(void* const* d_in, const int* in_sizes, int n_in,
                              void* d_out, int out_size, void* d_ws,
                              size_t ws_size, hipStream_t stream) {
  const float* hid = (const float*)d_in[0];
  const float* emb = (const float*)d_in[1];
  const float* temps = (const float*)d_in[2];
  const float* tops = (const float*)d_in[3];
  const int* topk = (const int*)d_in[4];
  float* outF = (float*)d_out;
  uint32_t* wsMax = (uint32_t*)d_ws;        // [64] ordered-uint row max
  float* wsM = (float*)d_ws + 64;           // [64]
  float* wsZ = (float*)d_ws + 128;          // [64]

  k_init<<<1, 64, 0, stream>>>(wsMax);
  k_gemm<<<(VV + 63) / 64, 256, 0, stream>>>(hid, emb, temps, outF, wsMax);
  k_sumexp<<<BB, 1024, 0, stream>>>(outF, wsMax, wsM, wsZ);
  k_select<<<BB, 1024, 0, stream>>>(outF, wsM, wsZ, tops, topk);
}